// Round 1
// baseline (762.983 us; speedup 1.0000x reference)
//
#include <hip/hip_runtime.h>

#define BB 4
#define SS 2048
#define DD 2048
#define HH 16
#define DHD 128
#define MAXL 1024

typedef __bf16 bf16x8 __attribute__((ext_vector_type(8)));
typedef float f32x4 __attribute__((ext_vector_type(4)));
typedef unsigned int u32_as1 __attribute__((address_space(1)));
typedef unsigned int u32_as3 __attribute__((address_space(3)));

__device__ __forceinline__ unsigned short f2bf(float f) {
  unsigned int u = __builtin_bit_cast(unsigned int, f);
  u += 0x7fffu + ((u >> 16) & 1u);   // RNE
  return (unsigned short)(u >> 16);
}
__device__ __forceinline__ float bf2f(unsigned short h) {
  unsigned int u = ((unsigned int)h) << 16;
  return __builtin_bit_cast(float, u);
}
union U4 { uint4 u; bf16x8 b; };
__device__ __forceinline__ bf16x8 ldfrag(const unsigned short* p) {
  U4 x; x.u = *(const uint4*)p; return x.b;
}
__device__ __forceinline__ void gl_lds16(const void* g, void* l) {
  __builtin_amdgcn_global_load_lds((const u32_as1*)g, (u32_as3*)l, 16, 0, 0);
}

// ---------------------------------------------------------------------------
__global__ void build_pos(const int* __restrict__ skip, int* __restrict__ posk,
                          int* __restrict__ nval) {
  int b = blockIdx.x, t = threadIdx.x;  // 64 threads
  __shared__ int cnts[64], offs[64];
  const int* row = skip + b * SS;
  int c = 0;
  for (int i = 0; i < 32; i++) c += (row[t * 32 + i] != 0);
  cnts[t] = c;
  __syncthreads();
  if (t == 0) {
    int run = 0;
    for (int i = 0; i < 64; i++) { offs[i] = run; run += cnts[i]; }
    nval[b] = run > MAXL ? MAXL : run;
  }
  __syncthreads();
  int o = offs[t];
  for (int i = 0; i < 32; i++)
    if (row[t * 32 + i]) { if (o < MAXL) posk[b * MAXL + o] = t * 32 + i; o++; }
  int nb = nval[b];
  for (int l = nb + t; l < MAXL; l += 64) posk[b * MAXL + l] = -1;
}

// ---------------------------------------------------------------------------
// fused fp32->bf16 for q_src/k_src/v_src. grid = (nq+nk+nv)/4/256 blocks.
__global__ __launch_bounds__(256) void cvt3(const float* __restrict__ q,
                                            const float* __restrict__ k,
                                            const float* __restrict__ v,
                                            unsigned short* __restrict__ oq,
                                            unsigned short* __restrict__ ok,
                                            unsigned short* __restrict__ ov) {
  const int nq = BB * MAXL * DD / 4, nk = BB * SS * DD / 4;
  int idx = blockIdx.x * 256 + threadIdx.x;
  const float* src; unsigned short* dst; int off;
  if (idx < nq) { src = q; dst = oq; off = idx; }
  else if (idx < nq + nk) { src = k; dst = ok; off = idx - nq; }
  else { src = v; dst = ov; off = idx - nq - nk; }
  float4 vv = ((const float4*)src)[off];
  ushort4 h;
  h.x = f2bf(vv.x); h.y = f2bf(vv.y); h.z = f2bf(vv.z); h.w = f2bf(vv.w);
  ((ushort4*)dst)[off] = h;
}

// ---------------------------------------------------------------------------
// 4 weight matrices [2048][2048] fp32 -> bf16 transposed, z picks the matrix.
__global__ __launch_bounds__(256) void transpose_w4(const float* __restrict__ w0,
    const float* __restrict__ w1, const float* __restrict__ w2, const float* __restrict__ w3,
    unsigned short* __restrict__ o0, unsigned short* __restrict__ o1,
    unsigned short* __restrict__ o2, unsigned short* __restrict__ o3) {
  __shared__ __align__(16) unsigned short tile[64 * 76];
  const float* W; unsigned short* Wt;
  switch (blockIdx.z) {
    case 0: W = w0; Wt = o0; break;
    case 1: W = w1; Wt = o1; break;
    case 2: W = w2; Wt = o2; break;
    default: W = w3; Wt = o3; break;
  }
  int tx = threadIdx.x;
  int K0 = blockIdx.y * 64, N0 = blockIdx.x * 64;
  #pragma unroll
  for (int i = 0; i < 4; i++) {
    int r = (tx >> 4) + i * 16, c4 = (tx & 15) * 4;
    float4 v = *(const float4*)&W[(size_t)(K0 + r) * DD + N0 + c4];
    ushort4 h;
    h.x = f2bf(v.x); h.y = f2bf(v.y); h.z = f2bf(v.z); h.w = f2bf(v.w);
    *(ushort4*)&tile[r * 76 + c4] = h;
  }
  __syncthreads();
  #pragma unroll
  for (int i = 0; i < 4; i++) {
    int n = (tx >> 4) + i * 16, k4 = (tx & 15) * 4;
    ushort4 h;
    h.x = tile[(k4 + 0) * 76 + n];
    h.y = tile[(k4 + 1) * 76 + n];
    h.z = tile[(k4 + 2) * 76 + n];
    h.w = tile[(k4 + 3) * 76 + n];
    *(ushort4*)&Wt[(size_t)(N0 + n) * DD + K0 + k4] = h;
  }
}

// ---------------------------------------------------------------------------
// 256x256-tile bf16 GEMM, BK=64, 512 threads (8 waves, 2M x 4N), 8-phase-style
// schedule: full-tile global_load_lds prefetch at iteration head, counted
// s_waitcnt vmcnt(8) (never 0 in main loop), raw s_barrier (no drain),
// XOR-swizzled LDS (ch ^= row&7 on 16B chunks, applied to the global SOURCE
// at stage time and to the ds_read address — involution, rule #21),
// s_setprio(1) around each 16-MFMA quadrant cluster.
// LDS: A[2][256][64] + B[2][256][64] bf16 = 128 KiB -> 1 block/CU.
// mode 0: head-split bf16 out [b][h][l][128] (LDS-bounce, coalesced dwordx4)
// mode 1: fp32 row-major [M][N] (direct)
// mode 2: V^T bf16 [b][h][d][S] (LDS-bounce transposed)
__global__ __launch_bounds__(512, 2) void gemm256(const unsigned short* __restrict__ A,
                                                  const unsigned short* __restrict__ Bt,
                                                  void* __restrict__ Cp,
                                                  int M, int N, int K, int mode, int Lbits) {
  __shared__ __align__(16) unsigned short lds[65536];  // 128 KiB

  const int tid = threadIdx.x;
  const int lane = tid & 63, quad = lane >> 4, c = lane & 15;
  const int w = tid >> 6;
  const int wm = (w >> 2) * 128, wn = (w & 3) * 64;

  // XCD-aware block swizzle (nwg is a multiple of 8 for all our launches)
  const int nwg = gridDim.x * gridDim.y;
  const int bid0 = blockIdx.y * gridDim.x + blockIdx.x;
  const int cpx = nwg >> 3;
  const int bid = (bid0 & 7) * cpx + (bid0 >> 3);
  const int bx = bid % gridDim.x;
  const int by = bid / gridDim.x;
  const size_t tm = (size_t)by * 256, tn = (size_t)bx * 256;

  f32x4 acc[8][4] = {};

  // staging: thread t stages LDS chunk (i*512+t) = (row = i*64 + t>>3, slot = t&7).
  // slot s at row r must hold global chunk (s ^ (r&7)); r&7 == (t>>3)&7 for all i.
  const int trow = tid >> 3;
  const int tch = ((tid & 7) ^ (trow & 7)) * 8;     // ushort offset of source chunk
  const unsigned short* gA = A + (tm + trow) * (size_t)K + tch;
  const unsigned short* gB = Bt + (tn + trow) * (size_t)K + tch;

  auto STAGE = [&](unsigned short* asd, unsigned short* bsd, int kk) {
    #pragma unroll
    for (int i = 0; i < 4; i++) {
      gl_lds16(gA + kk + (size_t)(i * 64) * K, asd + i * 4096 + tid * 8);
      gl_lds16(gB + kk + (size_t)(i * 64) * K, bsd + i * 4096 + tid * 8);
    }
  };

  const int nkt = K >> 6;
  STAGE(lds, lds + 32768, 0);

  for (int t = 0; t < nkt; ++t) {
    const int sel = t & 1;
    const unsigned short* as = lds + sel * 16384;
    const unsigned short* bs = lds + 32768 + sel * 16384;
    if (t + 1 < nkt) {
      const int s2 = sel ^ 1;
      STAGE(lds + s2 * 16384, lds + 32768 + s2 * 16384, (t + 1) << 6);
      asm volatile("s_waitcnt vmcnt(8)" ::: "memory");  // wait tile t only; t+1 in flight
    } else {
      asm volatile("s_waitcnt vmcnt(0)" ::: "memory");
    }
    __builtin_amdgcn_s_barrier();   // tile t resident block-wide

    bf16x8 af[4][2], ag[4][2], bfr[4][2];
    // ---- P1: ds_read A m0-3 + B n0-1; MFMA (m0-3 x n0-1)
    #pragma unroll
    for (int i = 0; i < 4; i++)
      #pragma unroll
      for (int ks = 0; ks < 2; ks++)
        af[i][ks] = ldfrag(&as[(wm + i * 16 + c) * 64 + (((ks * 4 + quad) ^ (c & 7)) << 3)]);
    #pragma unroll
    for (int j = 0; j < 2; j++)
      #pragma unroll
      for (int ks = 0; ks < 2; ks++)
        bfr[j][ks] = ldfrag(&bs[(wn + j * 16 + c) * 64 + (((ks * 4 + quad) ^ (c & 7)) << 3)]);
    __builtin_amdgcn_s_barrier();
    asm volatile("s_waitcnt lgkmcnt(0)" ::: "memory");
    __builtin_amdgcn_s_setprio(1);
    #pragma unroll
    for (int i = 0; i < 4; i++)
      #pragma unroll
      for (int j = 0; j < 2; j++)
        #pragma unroll
        for (int ks = 0; ks < 2; ks++)
          acc[i][j] = __builtin_amdgcn_mfma_f32_16x16x32_bf16(af[i][ks], bfr[j][ks], acc[i][j], 0, 0, 0);
    __builtin_amdgcn_s_setprio(0);
    __builtin_amdgcn_s_barrier();
    // ---- P2: ds_read B n2-3; MFMA (m0-3 x n2-3)
    #pragma unroll
    for (int j = 2; j < 4; j++)
      #pragma unroll
      for (int ks = 0; ks < 2; ks++)
        bfr[j][ks] = ldfrag(&bs[(wn + j * 16 + c) * 64 + (((ks * 4 + quad) ^ (c & 7)) << 3)]);
    __builtin_amdgcn_s_barrier();
    asm volatile("s_waitcnt lgkmcnt(0)" ::: "memory");
    __builtin_amdgcn_s_setprio(1);
    #pragma unroll
    for (int i = 0; i < 4; i++)
      #pragma unroll
      for (int j = 2; j < 4; j++)
        #pragma unroll
        for (int ks = 0; ks < 2; ks++)
          acc[i][j] = __builtin_amdgcn_mfma_f32_16x16x32_bf16(af[i][ks], bfr[j][ks], acc[i][j], 0, 0, 0);
    __builtin_amdgcn_s_setprio(0);
    __builtin_amdgcn_s_barrier();
    // ---- P3: ds_read A m4-7; MFMA (m4-7 x n0-1)
    #pragma unroll
    for (int i = 0; i < 4; i++)
      #pragma unroll
      for (int ks = 0; ks < 2; ks++)
        ag[i][ks] = ldfrag(&as[(wm + 64 + i * 16 + c) * 64 + (((ks * 4 + quad) ^ (c & 7)) << 3)]);
    __builtin_amdgcn_s_barrier();
    asm volatile("s_waitcnt lgkmcnt(0)" ::: "memory");
    __builtin_amdgcn_s_setprio(1);
    #pragma unroll
    for (int i = 0; i < 4; i++)
      #pragma unroll
      for (int j = 0; j < 2; j++)
        #pragma unroll
        for (int ks = 0; ks < 2; ks++)
          acc[4 + i][j] = __builtin_amdgcn_mfma_f32_16x16x32_bf16(ag[i][ks], bfr[j][ks], acc[4 + i][j], 0, 0, 0);
    __builtin_amdgcn_s_setprio(0);
    __builtin_amdgcn_s_barrier();
    // ---- P4: MFMA (m4-7 x n2-3), no new ds_reads
    __builtin_amdgcn_s_setprio(1);
    #pragma unroll
    for (int i = 0; i < 4; i++)
      #pragma unroll
      for (int j = 2; j < 4; j++)
        #pragma unroll
        for (int ks = 0; ks < 2; ks++)
          acc[4 + i][j] = __builtin_amdgcn_mfma_f32_16x16x32_bf16(ag[i][ks], bfr[j][ks], acc[4 + i][j], 0, 0, 0);
    __builtin_amdgcn_s_setprio(0);
    __builtin_amdgcn_s_barrier();   // all reads of buf[sel] retired before next stage
  }

  // ---- epilogue: staging LDS is dead; per-wave 16 KB bounce regions
  if (mode == 1) {
    float* Cf = (float*)Cp;
    #pragma unroll
    for (int i = 0; i < 8; i++)
      #pragma unroll
      for (int j = 0; j < 4; j++)
        #pragma unroll
        for (int r = 0; r < 4; r++) {
          size_t m = tm + wm + i * 16 + quad * 4 + r;
          size_t n = tn + wn + j * 16 + c;
          Cf[m * N + n] = acc[i][j][r];
        }
    return;
  }
  unsigned short* Cb = (unsigned short*)Cp;
  unsigned short* ep = lds + w * 8192;   // per-wave [64][68] bounce tile
  if (mode == 0) {
    const size_t Lmask = ((size_t)1 << Lbits) - 1;
    #pragma unroll
    for (int mh = 0; mh < 2; mh++) {
      #pragma unroll
      for (int i = 0; i < 4; i++)
        #pragma unroll
        for (int j = 0; j < 4; j++)
          #pragma unroll
          for (int r = 0; r < 4; r++)
            ep[(i * 16 + quad * 4 + r) * 68 + j * 16 + c] = f2bf(acc[mh * 4 + i][j][r]);
      #pragma unroll
      for (int it = 0; it < 8; it++) {
        int chunk = it * 64 + lane;
        int ml = chunk >> 3, nc = (chunk & 7) * 8;
        uint4 val = *(const uint4*)&ep[ml * 68 + nc];
        size_t m = tm + wm + mh * 64 + ml, n = tn + wn + nc;
        size_t b = m >> Lbits, l = m & Lmask, h = n >> 7, d = n & 127;
        *(uint4*)&Cb[(((b * HH + h) << Lbits) + l) * 128 + d] = val;
      }
    }
  } else {
    // mode 2: stage transposed [n][m], write V^T [b][h][d][S]
    #pragma unroll
    for (int mh = 0; mh < 2; mh++) {
      #pragma unroll
      for (int i = 0; i < 4; i++)
        #pragma unroll
        for (int j = 0; j < 4; j++)
          #pragma unroll
          for (int r = 0; r < 4; r++)
            ep[(j * 16 + c) * 68 + i * 16 + quad * 4 + r] = f2bf(acc[mh * 4 + i][j][r]);
      #pragma unroll
      for (int it = 0; it < 8; it++) {
        int chunk = it * 64 + lane;
        int nl = chunk >> 3, mc = (chunk & 7) * 8;
        uint4 val = *(const uint4*)&ep[nl * 68 + mc];
        size_t n = tn + wn + nl, m = tm + wm + mh * 64 + mc;
        size_t b = m >> 11, s = m & 2047, h = n >> 7, d = n & 127;
        *(uint4*)&Cb[((b * HH + h) * 128 + d) * SS + s] = val;
      }
    }
  }
}

// ---------------------------------------------------------------------------
// fused RoPE: first Nq threads handle Q (trimmed positions), rest handle K.
__global__ __launch_bounds__(256) void rope2(unsigned short* __restrict__ xq,
                                             unsigned short* __restrict__ xk,
                                             const int* __restrict__ posk) {
  const int Nq = BB * HH * MAXL * 64;
  int gid = blockIdx.x * 256 + threadIdx.x;
  unsigned short* x; int Lbits, idx, use_posk;
  if (gid < Nq) { x = xq; Lbits = 10; use_posk = 1; idx = gid; }
  else { x = xk; Lbits = 11; use_posk = 0; idx = gid - Nq; }
  int d = idx & 63;
  int rest = idx >> 6;
  int l = rest & ((1 << Lbits) - 1);
  int bh = rest >> Lbits;
  int b = bh >> 4;
  int p = use_posk ? posk[(b << 10) + l] : l;
  float ang = (float)p * __expf(-(float)d * 0.14391156831212787f); // ln(1e4)/64
  float sn, cs;
  __sincosf(ang, &sn, &cs);
  size_t base = (size_t)rest * 128;
  float x1 = bf2f(x[base + d]), x2 = bf2f(x[base + d + 64]);
  x[base + d]      = f2bf(x1 * cs - x2 * sn);
  x[base + d + 64] = f2bf(x2 * cs + x1 * sn);
}

// ---------------------------------------------------------------------------
// Flash attention. Grid: (bh 64, qtile 16) — bh fastest so all q-tiles of one
// bh map to the same XCD (round-robin by linear block id) for K/V L2 reuse.
// K and V^T staged via global_load_lds with XOR-swizzled source chunks:
// LDS slot (row, ch) holds global chunk (row, ch ^ (row&7)) -> b128 frag reads
// are perfectly bank-spread. Q fragments live in registers.
__global__ __launch_bounds__(256) void attn_kernel(const unsigned short* __restrict__ qp,
                                                   const unsigned short* __restrict__ kp,
                                                   const unsigned short* __restrict__ vtp,
                                                   const int* __restrict__ posk,
                                                   const int* __restrict__ nval,
                                                   unsigned short* __restrict__ ctx) {
  __shared__ __align__(16) unsigned short k_s[64 * 128];   // [s][d] swizzled
  __shared__ __align__(16) unsigned short vt_s[128 * 64];  // [d][s] swizzled
  __shared__ __align__(16) unsigned short p_s[4 * 16 * 72];
  __shared__ int km_s[64];

  const int tid = threadIdx.x;
  const int w = tid >> 6, lane = tid & 63, quad = lane >> 4, c = lane & 15;
  const int bh = blockIdx.x, b = bh >> 4, h = bh & 15;
  const int qbase = blockIdx.y * 64;
  const int nb = nval[b];

  if (tid < 64) {
    int l = qbase + tid;
    km_s[tid] = (l < nb) ? posk[(b << 10) + l] : -1;
  }
  __syncthreads();

  // Q fragments in registers (A-layout: m = c, k = ks*32 + quad*8 + j)
  const unsigned short* qg = qp + (((size_t)bh << 10) + qbase) * 128;
  bf16x8 aq[4];
  #pragma unroll
  for (int ks = 0; ks < 4; ks++)
    aq[ks] = ldfrag(&qg[(size_t)(w * 16 + c) * 128 + ks * 32 + quad * 8]);

  int lv = nb - 1 - qbase; lv = lv > 63 ? 63 : lv;
  const int tile_kmax = (lv >= 0) ? km_s[lv] : -1;
  const int nkt = (tile_kmax >= 0) ? ((tile_kmax >> 6) + 1) : 0;

  int km[4];
  #pragma unroll
  for (int r = 0; r < 4; r++) km[r] = km_s[w * 16 + quad * 4 + r];

  // staging source pointers (swizzle keys constant across the i-unroll)
  const int srow = tid >> 4;                       // K: s-local row 0..15 (+16i)
  const int kswz = (tid & 15) ^ (srow & 7);
  const unsigned short* kgp = kp + ((size_t)bh << 11) * 128 + (size_t)srow * 128 + kswz * 8;
  const int dvrow = tid >> 3;                      // V: d-local row 0..31 (+32i)
  const int vswz = (tid & 7) ^ (dvrow & 7);
  const unsigned short* vgp = vtp + ((size_t)bh * 128 + dvrow) * SS + vswz * 8;

  float m_i[4], l_i[4];
  #pragma unroll
  for (int r = 0; r < 4; r++) { m_i[r] = -1e30f; l_i[r] = 0.f; }
  f32x4 o[8];
  #pragma unroll
  for (int dj = 0; dj < 8; dj++) o[dj] = (f32x4){0.f, 0.f, 0.f, 0.f};

  for (int kt = 0; kt < nkt; kt++) {
    const int kb = kt * 64;
    __syncthreads();   // previous tile's LDS reads complete
    #pragma unroll
    for (int i = 0; i < 4; i++)
      gl_lds16(kgp + ((size_t)kb + i * 16) * 128, &k_s[(i * 256 + tid) * 8]);
    #pragma unroll
    for (int i = 0; i < 4; i++)
      gl_lds16(vgp + (size_t)kb + (size_t)i * 32 * SS, &vt_s[(i * 256 + tid) * 8]);
    __syncthreads();   // drains vmcnt

    // S = Q K^T
    f32x4 sa[4];
    #pragma unroll
    for (int j = 0; j < 4; j++) {
      sa[j] = (f32x4){0.f, 0.f, 0.f, 0.f};
      #pragma unroll
      for (int ks = 0; ks < 4; ks++) {
        bf16x8 bk = ldfrag(&k_s[((j * 16 + c) << 7) + (((ks * 4 + quad) ^ (c & 7)) << 3)]);
        sa[j] = __builtin_amdgcn_mfma_f32_16x16x32_bf16(aq[ks], bk, sa[j], 0, 0, 0);
      }
    }

    // online softmax (rows live in quads; reduce over the 16 lanes of a quad)
    const float scale = 0.08838834764831843f;  // 1/sqrt(128)
    float mt[4] = {-1e30f, -1e30f, -1e30f, -1e30f};
    #pragma unroll
    for (int j = 0; j < 4; j++) {
      int key = kb + j * 16 + c;
      #pragma unroll
      for (int r = 0; r < 4; r++) {
        float v = (key <= km[r]) ? sa[j][r] * scale : -1e30f;
        sa[j][r] = v;
        mt[r] = fmaxf(mt[r], v);
      }
    }
    #pragma unroll
    for (int r = 0; r < 4; r++)
      for (int off = 1; off < 16; off <<= 1)
        mt[r] = fmaxf(mt[r], __shfl_xor(mt[r], off, 16));
    float al[4], rs[4];
    #pragma unroll
    for (int r = 0; r < 4; r++) {
      float mn = fmaxf(m_i[r], mt[r]);
      al[r] = __expf(m_i[r] - mn);
      m_i[r] = mn;
      rs[r] = 0.f;
    }
    #pragma unroll
    for (int j = 0; j < 4; j++)
      #pragma unroll
      for (int r = 0; r < 4; r++) {
        float pv = __expf(sa[j][r] - m_i[r]);
        sa[j][r] = pv;
        rs[r] += pv;
      }
    #pragma unroll
    for (int r = 0; r < 4; r++) {
      for (int off = 1; off < 16; off <<= 1) rs[r] += __shfl_xor(rs[r], off, 16);
      l_i[r] = l_i[r] * al[r] + rs[r];
    }
    #pragma unroll
    for (int dj = 0; dj < 8; dj++)
      #pragma unroll
      for (int r = 0; r < 4; r++) o[dj][r] *= al[r];

    // P: C-layout -> LDS -> A-layout (per-wave region)
    #pragma unroll
    for (int j = 0; j < 4; j++)
      #pragma unroll
      for (int r = 0; r < 4; r++)
        p_s[w * 1152 + (quad * 4 + r) * 72 + j * 16 + c] = f2bf(sa[j][r]);

    #pragma unroll
    for (int ks2 = 0; ks2 < 2; ks2++) {
      bf16x8 ap = ldfrag(&p_s[w * 1152 + c * 72 + ks2 * 32 + quad * 8]);
      #pragma unroll
      for (int dj = 0; dj < 8; dj++) {
        bf16x8 bv = ldfrag(&vt_s[((dj * 16 + c) << 6) + (((ks2 * 4 + quad) ^ (c & 7)) << 3)]);
        o[dj] = __builtin_amdgcn_mfma_f32_16x16x32_bf16(ap, bv, o[dj], 0, 0, 0);
      }
    }
  }

  #pragma unroll
  for (int r = 0; r < 4; r++) {
    int l = qbase + w * 16 + quad * 4 + r;
    bool ok = (l < nb);
    float inv = ok ? (1.0f / l_i[r]) : 0.0f;
    #pragma unroll
    for (int dj = 0; dj < 8; dj++)
      ctx[(((size_t)b << 10) + l) * (size_t)DD + h * 128 + dj * 16 + c] =
          f2bf(ok ? o[dj][r] * inv : 0.0f);
  }
}

// ---------------------------------------------------------------------------
extern "C" void kernel_launch(void* const* d_in, const int* in_sizes, int n_in,
                              void* d_out, int out_size, void* d_ws, size_t ws_size,
                              hipStream_t stream) {
  const float* q_src = (const float*)d_in[0];
  const float* k_src = (const float*)d_in[1];
  const float* v_src = (const float*)d_in[2];
  const float* Wq = (const float*)d_in[3];
  const float* Wk = (const float*)d_in[4];
  const float* Wv = (const float*)d_in[5];
  const float* Wo = (const float*)d_in[6];
  const int* skip = (const int*)d_in[9];

  char* p = (char*)d_ws;
  auto alloc = [&](size_t bytes) -> char* {
    char* r = p;
    p += (bytes + 255) & ~(size_t)255;
    return r;
  };
  unsigned short* a_q  = (unsigned short*)alloc((size_t)BB * MAXL * DD * 2);
  unsigned short* a_k  = (unsigned short*)alloc((size_t)BB * SS * DD * 2);
  unsigned short* a_v  = (unsigned short*)alloc((size_t)BB * SS * DD * 2);
  unsigned short* wt_q = (unsigned short*)alloc((size_t)DD * DD * 2);
  unsigned short* wt_k = (unsigned short*)alloc((size_t)DD * DD * 2);
  unsigned short* wt_v = (unsigned short*)alloc((size_t)DD * DD * 2);
  unsigned short* wt_o = (unsigned short*)alloc((size_t)DD * DD * 2);
  unsigned short* q_pro = (unsigned short*)alloc((size_t)BB * HH * MAXL * DHD * 2);
  unsigned short* k_pro = (unsigned short*)alloc((size_t)BB * HH * SS * DHD * 2);
  unsigned short* v_t   = (unsigned short*)alloc((size_t)BB * HH * SS * DHD * 2);
  int* posk = (int*)alloc((size_t)BB * MAXL * 4);
  int* nval = (int*)alloc(64);
  unsigned short* ctx = a_q;  // a_q dead after Q projection

  build_pos<<<BB, 64, 0, stream>>>(skip, posk, nval);
  cvt3<<<(BB * MAXL * DD + 2 * BB * SS * DD) / (4 * 256), 256, 0, stream>>>(
      q_src, k_src, v_src, a_q, a_k, a_v);
  transpose_w4<<<dim3(32, 32, 4), 256, 0, stream>>>(Wq, Wk, Wv, Wo, wt_q, wt_k, wt_v, wt_o);

  gemm256<<<dim3(8, 16), 512, 0, stream>>>(a_q, wt_q, q_pro, BB * MAXL, DD, DD, 0, 10);
  gemm256<<<dim3(8, 32), 512, 0, stream>>>(a_k, wt_k, k_pro, BB * SS, DD, DD, 0, 11);
  gemm256<<<dim3(8, 32), 512, 0, stream>>>(a_v, wt_v, v_t, BB * SS, DD, DD, 2, 11);

  rope2<<<(BB * HH * (MAXL + SS) * 64) / 256, 256, 0, stream>>>(q_pro, k_pro, posk);

  attn_kernel<<<dim3(BB * HH, MAXL / 64), 256, 0, stream>>>(q_pro, k_pro, v_t, posk, nval, ctx);

  gemm256<<<dim3(8, 16), 512, 0, stream>>>(ctx, wt_o, d_out, BB * MAXL, DD, DD, 1, 0);
}

// Round 2
// 692.680 us; speedup vs baseline: 1.1015x; 1.1015x over previous
//
#include <hip/hip_runtime.h>

#define BB 4
#define SS 2048
#define DD 2048
#define HH 16
#define DHD 128
#define MAXL 1024

typedef __bf16 bf16x8 __attribute__((ext_vector_type(8)));
typedef float f32x4 __attribute__((ext_vector_type(4)));
typedef unsigned int u32_as1 __attribute__((address_space(1)));
typedef unsigned int u32_as3 __attribute__((address_space(3)));

__device__ __forceinline__ unsigned short f2bf(float f) {
  unsigned int u = __builtin_bit_cast(unsigned int, f);
  u += 0x7fffu + ((u >> 16) & 1u);   // RNE
  return (unsigned short)(u >> 16);
}
__device__ __forceinline__ float bf2f(unsigned short h) {
  unsigned int u = ((unsigned int)h) << 16;
  return __builtin_bit_cast(float, u);
}
union U4 { uint4 u; bf16x8 b; };
__device__ __forceinline__ bf16x8 ldfrag(const unsigned short* p) {
  U4 x; x.u = *(const uint4*)p; return x.b;
}
__device__ __forceinline__ void gl_lds16(const void* g, void* l) {
  __builtin_amdgcn_global_load_lds((const u32_as1*)g, (u32_as3*)l, 16, 0, 0);
}

// DPP 16-lane butterfly reduction (VALU, replaces ds_bpermute shfl chains).
// 0xB1=quad_perm[1,0,3,2](xor1) 0x4E=quad_perm[2,3,0,1](xor2)
// 0x141=ROW_HALF_MIRROR 0x140=ROW_MIRROR — valid for group-uniform reduce.
template <int C>
__device__ __forceinline__ float dppf(float x) {
  return __builtin_bit_cast(float,
      __builtin_amdgcn_mov_dpp(__builtin_bit_cast(int, x), C, 0xF, 0xF, true));
}
__device__ __forceinline__ float rmax16(float x) {
  x = fmaxf(x, dppf<0xB1>(x));
  x = fmaxf(x, dppf<0x4E>(x));
  x = fmaxf(x, dppf<0x141>(x));
  x = fmaxf(x, dppf<0x140>(x));
  return x;
}
__device__ __forceinline__ float radd16(float x) {
  x += dppf<0xB1>(x);
  x += dppf<0x4E>(x);
  x += dppf<0x141>(x);
  x += dppf<0x140>(x);
  return x;
}

// ---------------------------------------------------------------------------
__global__ void build_pos(const int* __restrict__ skip, int* __restrict__ posk,
                          int* __restrict__ nval) {
  int b = blockIdx.x, t = threadIdx.x;  // 64 threads
  __shared__ int cnts[64], offs[64];
  const int* row = skip + b * SS;
  int c = 0;
  for (int i = 0; i < 32; i++) c += (row[t * 32 + i] != 0);
  cnts[t] = c;
  __syncthreads();
  if (t == 0) {
    int run = 0;
    for (int i = 0; i < 64; i++) { offs[i] = run; run += cnts[i]; }
    nval[b] = run > MAXL ? MAXL : run;
  }
  __syncthreads();
  int o = offs[t];
  for (int i = 0; i < 32; i++)
    if (row[t * 32 + i]) { if (o < MAXL) posk[b * MAXL + o] = t * 32 + i; o++; }
  int nb = nval[b];
  for (int l = nb + t; l < MAXL; l += 64) posk[b * MAXL + l] = -1;
}

// ---------------------------------------------------------------------------
// fused fp32->bf16 for q_src/k_src/v_src. grid = (nq+nk+nv)/4/256 blocks.
__global__ __launch_bounds__(256) void cvt3(const float* __restrict__ q,
                                            const float* __restrict__ k,
                                            const float* __restrict__ v,
                                            unsigned short* __restrict__ oq,
                                            unsigned short* __restrict__ ok,
                                            unsigned short* __restrict__ ov) {
  const int nq = BB * MAXL * DD / 4, nk = BB * SS * DD / 4;
  int idx = blockIdx.x * 256 + threadIdx.x;
  const float* src; unsigned short* dst; int off;
  if (idx < nq) { src = q; dst = oq; off = idx; }
  else if (idx < nq + nk) { src = k; dst = ok; off = idx - nq; }
  else { src = v; dst = ov; off = idx - nq - nk; }
  float4 vv = ((const float4*)src)[off];
  ushort4 h;
  h.x = f2bf(vv.x); h.y = f2bf(vv.y); h.z = f2bf(vv.z); h.w = f2bf(vv.w);
  ((ushort4*)dst)[off] = h;
}

// ---------------------------------------------------------------------------
// 4 weight matrices [2048][2048] fp32 -> bf16 transposed, z picks the matrix.
__global__ __launch_bounds__(256) void transpose_w4(const float* __restrict__ w0,
    const float* __restrict__ w1, const float* __restrict__ w2, const float* __restrict__ w3,
    unsigned short* __restrict__ o0, unsigned short* __restrict__ o1,
    unsigned short* __restrict__ o2, unsigned short* __restrict__ o3) {
  __shared__ __align__(16) unsigned short tile[64 * 76];
  const float* W; unsigned short* Wt;
  switch (blockIdx.z) {
    case 0: W = w0; Wt = o0; break;
    case 1: W = w1; Wt = o1; break;
    case 2: W = w2; Wt = o2; break;
    default: W = w3; Wt = o3; break;
  }
  int tx = threadIdx.x;
  int K0 = blockIdx.y * 64, N0 = blockIdx.x * 64;
  #pragma unroll
  for (int i = 0; i < 4; i++) {
    int r = (tx >> 4) + i * 16, c4 = (tx & 15) * 4;
    float4 v = *(const float4*)&W[(size_t)(K0 + r) * DD + N0 + c4];
    ushort4 h;
    h.x = f2bf(v.x); h.y = f2bf(v.y); h.z = f2bf(v.z); h.w = f2bf(v.w);
    *(ushort4*)&tile[r * 76 + c4] = h;
  }
  __syncthreads();
  #pragma unroll
  for (int i = 0; i < 4; i++) {
    int n = (tx >> 4) + i * 16, k4 = (tx & 15) * 4;
    ushort4 h;
    h.x = tile[(k4 + 0) * 76 + n];
    h.y = tile[(k4 + 1) * 76 + n];
    h.z = tile[(k4 + 2) * 76 + n];
    h.w = tile[(k4 + 3) * 76 + n];
    *(ushort4*)&Wt[(size_t)(N0 + n) * DD + K0 + k4] = h;
  }
}

// ---------------------------------------------------------------------------
// BMx256-tile bf16 GEMM (BM=256 for M=8192, BM=128 for M=4096 -> 256 blocks),
// BK=64, 512 threads (8 waves, 2M x 4N). Double-buffered global_load_lds with
// XOR-swizzled source chunks + counted s_waitcnt vmcnt(N) (never 0 mid-loop),
// raw s_barrier phases, s_setprio around MFMA clusters. Compiler handles
// lgkm waits precisely (no manual lgkmcnt(0) drains).
// mode 0: head-split bf16 [b][h][l][128]; mode 1: fp32 [M][N]; mode 2: V^T.
template <int BM>
__global__ __launch_bounds__(512, 2) void gemm8(const unsigned short* __restrict__ A,
                                                const unsigned short* __restrict__ Bt,
                                                void* __restrict__ Cp,
                                                int M, int N, int K, int mode, int Lbits) {
  constexpr int AW = BM * 64;                  // ushorts per A buffer
  __shared__ __align__(16) unsigned short lds[(BM + 256) * 64 * 2];
  unsigned short* const Abuf = lds;            // [2][BM][64]
  unsigned short* const Bbuf = lds + 2 * AW;   // [2][256][64]

  const int tid = threadIdx.x;
  const int lane = tid & 63, quad = lane >> 4, c = lane & 15;
  const int w = tid >> 6;
  const int wm = (w >> 2) * (BM / 2), wn = (w & 3) * 64;

  // XCD-aware block swizzle (nwg multiple of 8 for all launches)
  const int nwg = gridDim.x * gridDim.y;
  const int bid0 = blockIdx.y * gridDim.x + blockIdx.x;
  const int cpx = nwg >> 3;
  const int bid = (bid0 & 7) * cpx + (bid0 >> 3);
  const int bx = bid % gridDim.x;
  const int by = bid / gridDim.x;
  const size_t tm = (size_t)by * BM, tn = (size_t)bx * 256;

  constexpr int MR = BM / 32;                  // acc m-frags per wave (8 or 4)
  f32x4 acc[MR][4] = {};

  // staging: thread t -> LDS chunk (row = i*64 + t>>3, slot = t&7); slot s at
  // row r holds global chunk s ^ (r&7)  (involution, read applies same XOR).
  const int trow = tid >> 3;
  const int tch = ((tid & 7) ^ (trow & 7)) * 8;
  const unsigned short* gA = A + (tm + trow) * (size_t)K + tch;
  const unsigned short* gB = Bt + (tn + trow) * (size_t)K + tch;
  constexpr int ALD = BM / 64;                 // A loads/thread (4 or 2)
  constexpr int NLD = ALD + 4;                 // loads per STAGE per thread

  auto STAGE = [&](int sel, int kk) {
    unsigned short* ad = Abuf + sel * AW;
    unsigned short* bd = Bbuf + sel * 16384;
    #pragma unroll
    for (int i = 0; i < ALD; i++)
      gl_lds16(gA + kk + (size_t)(i * 64) * K, ad + i * 4096 + tid * 8);
    #pragma unroll
    for (int i = 0; i < 4; i++)
      gl_lds16(gB + kk + (size_t)(i * 64) * K, bd + i * 4096 + tid * 8);
  };

  const int nkt = K >> 6;
  STAGE(0, 0);

  for (int t = 0; t < nkt; ++t) {
    const int sel = t & 1;
    const unsigned short* as = Abuf + sel * AW;
    const unsigned short* bs = Bbuf + sel * 16384;
    if (t + 1 < nkt) {
      STAGE(sel ^ 1, (t + 1) << 6);
      asm volatile("s_waitcnt vmcnt(%0)" ::"i"(NLD) : "memory");  // tile t landed
    } else {
      asm volatile("s_waitcnt vmcnt(0)" ::: "memory");
    }
    __builtin_amdgcn_s_barrier();

    bf16x8 a0[4][2], b01[2][2], b23[2][2];
    // ---- P1: ds_read A m-half0 + B j01; MFMA (m0 x j01)
    #pragma unroll
    for (int i = 0; i < 4; i++)
      #pragma unroll
      for (int ks = 0; ks < 2; ks++)
        a0[i][ks] = ldfrag(&as[(wm + i * 16 + c) * 64 + (((ks * 4 + quad) ^ (c & 7)) << 3)]);
    #pragma unroll
    for (int j = 0; j < 2; j++)
      #pragma unroll
      for (int ks = 0; ks < 2; ks++)
        b01[j][ks] = ldfrag(&bs[(wn + j * 16 + c) * 64 + (((ks * 4 + quad) ^ (c & 7)) << 3)]);
    __builtin_amdgcn_s_barrier();
    __builtin_amdgcn_s_setprio(1);
    #pragma unroll
    for (int i = 0; i < 4; i++)
      #pragma unroll
      for (int j = 0; j < 2; j++)
        #pragma unroll
        for (int ks = 0; ks < 2; ks++)
          acc[i][j] = __builtin_amdgcn_mfma_f32_16x16x32_bf16(a0[i][ks], b01[j][ks], acc[i][j], 0, 0, 0);
    __builtin_amdgcn_s_setprio(0);
    __builtin_amdgcn_s_barrier();
    // ---- P2: ds_read B j23; MFMA (m0 x j23)
    #pragma unroll
    for (int j = 0; j < 2; j++)
      #pragma unroll
      for (int ks = 0; ks < 2; ks++)
        b23[j][ks] = ldfrag(&bs[(wn + 32 + j * 16 + c) * 64 + (((ks * 4 + quad) ^ (c & 7)) << 3)]);
    __builtin_amdgcn_s_barrier();
    __builtin_amdgcn_s_setprio(1);
    #pragma unroll
    for (int i = 0; i < 4; i++)
      #pragma unroll
      for (int j = 0; j < 2; j++)
        #pragma unroll
        for (int ks = 0; ks < 2; ks++)
          acc[i][2 + j] = __builtin_amdgcn_mfma_f32_16x16x32_bf16(a0[i][ks], b23[j][ks], acc[i][2 + j], 0, 0, 0);
    __builtin_amdgcn_s_setprio(0);
    __builtin_amdgcn_s_barrier();

    if constexpr (BM == 256) {
      // ---- P3: ds_read A m-half1; MFMA (m1 x j01)
      bf16x8 a1[4][2];
      #pragma unroll
      for (int i = 0; i < 4; i++)
        #pragma unroll
        for (int ks = 0; ks < 2; ks++)
          a1[i][ks] = ldfrag(&as[(wm + 64 + i * 16 + c) * 64 + (((ks * 4 + quad) ^ (c & 7)) << 3)]);
      __builtin_amdgcn_s_barrier();
      __builtin_amdgcn_s_setprio(1);
      #pragma unroll
      for (int i = 0; i < 4; i++)
        #pragma unroll
        for (int j = 0; j < 2; j++)
          #pragma unroll
          for (int ks = 0; ks < 2; ks++)
            acc[4 + i][j] = __builtin_amdgcn_mfma_f32_16x16x32_bf16(a1[i][ks], b01[j][ks], acc[4 + i][j], 0, 0, 0);
      __builtin_amdgcn_s_setprio(0);
      __builtin_amdgcn_s_barrier();
      // ---- P4: MFMA (m1 x j23)
      __builtin_amdgcn_s_setprio(1);
      #pragma unroll
      for (int i = 0; i < 4; i++)
        #pragma unroll
        for (int j = 0; j < 2; j++)
          #pragma unroll
          for (int ks = 0; ks < 2; ks++)
            acc[4 + i][2 + j] = __builtin_amdgcn_mfma_f32_16x16x32_bf16(a1[i][ks], b23[j][ks], acc[4 + i][2 + j], 0, 0, 0);
      __builtin_amdgcn_s_setprio(0);
      __builtin_amdgcn_s_barrier();   // buf[sel] reads retired before next STAGE
    }
  }

  // ---- epilogue: staging LDS dead; per-wave 64x68 bounce regions
  if (mode == 1) {
    float* Cf = (float*)Cp;
    #pragma unroll
    for (int i = 0; i < MR; i++)
      #pragma unroll
      for (int j = 0; j < 4; j++)
        #pragma unroll
        for (int r = 0; r < 4; r++) {
          size_t m = tm + wm + i * 16 + quad * 4 + r;
          size_t n = tn + wn + j * 16 + c;
          Cf[m * N + n] = acc[i][j][r];
        }
    return;
  }
  unsigned short* Cb = (unsigned short*)Cp;
  unsigned short* ep = lds + w * 4352;   // per-wave [64][68] bounce tile
  constexpr int MH = BM / 128;           // 64-row halves per wave (2 or 1)
  if (mode == 0) {
    const size_t Lmask = ((size_t)1 << Lbits) - 1;
    #pragma unroll
    for (int mh = 0; mh < MH; mh++) {
      #pragma unroll
      for (int i = 0; i < 4; i++)
        #pragma unroll
        for (int j = 0; j < 4; j++)
          #pragma unroll
          for (int r = 0; r < 4; r++)
            ep[(i * 16 + quad * 4 + r) * 68 + j * 16 + c] = f2bf(acc[mh * 4 + i][j][r]);
      #pragma unroll
      for (int it = 0; it < 8; it++) {
        int chunk = it * 64 + lane;
        int ml = chunk >> 3, nc = (chunk & 7) * 8;
        uint4 val = *(const uint4*)&ep[ml * 68 + nc];
        size_t m = tm + wm + mh * 64 + ml, n = tn + wn + nc;
        size_t b = m >> Lbits, l = m & Lmask, h = n >> 7, d = n & 127;
        *(uint4*)&Cb[(((b * HH + h) << Lbits) + l) * 128 + d] = val;
      }
    }
  } else {
    // mode 2: stage transposed [n][m], write V^T [b][h][d][S]
    #pragma unroll
    for (int mh = 0; mh < MH; mh++) {
      #pragma unroll
      for (int i = 0; i < 4; i++)
        #pragma unroll
        for (int j = 0; j < 4; j++)
          #pragma unroll
          for (int r = 0; r < 4; r++)
            ep[(j * 16 + c) * 68 + i * 16 + quad * 4 + r] = f2bf(acc[mh * 4 + i][j][r]);
      #pragma unroll
      for (int it = 0; it < 8; it++) {
        int chunk = it * 64 + lane;
        int nl = chunk >> 3, mc = (chunk & 7) * 8;
        uint4 val = *(const uint4*)&ep[nl * 68 + mc];
        size_t n = tn + wn + nl, m = tm + wm + mh * 64 + mc;
        size_t b = m >> 11, s = m & 2047, h = n >> 7, d = n & 127;
        *(uint4*)&Cb[((b * HH + h) * 128 + d) * SS + s] = val;
      }
    }
  }
}

// ---------------------------------------------------------------------------
// fused RoPE: first Nq threads handle Q (trimmed positions), rest handle K.
__global__ __launch_bounds__(256) void rope2(unsigned short* __restrict__ xq,
                                             unsigned short* __restrict__ xk,
                                             const int* __restrict__ posk) {
  const int Nq = BB * HH * MAXL * 64;
  int gid = blockIdx.x * 256 + threadIdx.x;
  unsigned short* x; int Lbits, idx, use_posk;
  if (gid < Nq) { x = xq; Lbits = 10; use_posk = 1; idx = gid; }
  else { x = xk; Lbits = 11; use_posk = 0; idx = gid - Nq; }
  int d = idx & 63;
  int rest = idx >> 6;
  int l = rest & ((1 << Lbits) - 1);
  int bh = rest >> Lbits;
  int b = bh >> 4;
  int p = use_posk ? posk[(b << 10) + l] : l;
  float ang = (float)p * __expf(-(float)d * 0.14391156831212787f); // ln(1e4)/64
  float sn, cs;
  __sincosf(ang, &sn, &cs);
  size_t base = (size_t)rest * 128;
  float x1 = bf2f(x[base + d]), x2 = bf2f(x[base + d + 64]);
  x[base + d]      = f2bf(x1 * cs - x2 * sn);
  x[base + d + 64] = f2bf(x2 * cs + x1 * sn);
}

// ---------------------------------------------------------------------------
// Flash attention, pipelined: double-buffered K/V staging via global_load_lds
// with counted s_waitcnt vmcnt(8) (never 0 mid-loop) + raw s_barrier (no
// drain). DPP butterfly softmax reduces (VALU) replace shfl_xor (LDS pipe).
// Per-wave causal early-out: rows sorted ascending, wave w skips key tiles
// beyond km_s[w*16+15] (still participates in staging + barriers).
// Grid: (bh 64, qtile 16) — bh fastest so q-tiles of one bh share an XCD L2.
__global__ __launch_bounds__(256) void attn_kernel(const unsigned short* __restrict__ qp,
                                                   const unsigned short* __restrict__ kp,
                                                   const unsigned short* __restrict__ vtp,
                                                   const int* __restrict__ posk,
                                                   const int* __restrict__ nval,
                                                   unsigned short* __restrict__ ctx) {
  __shared__ __align__(16) unsigned short k_s[2][64 * 128];   // [s][d] swizzled
  __shared__ __align__(16) unsigned short vt_s[2][128 * 64];  // [d][s] swizzled
  __shared__ __align__(16) unsigned short p_s[4 * 16 * 72];
  __shared__ int km_s[64];

  const int tid = threadIdx.x;
  const int w = tid >> 6, lane = tid & 63, quad = lane >> 4, c = lane & 15;
  const int bh = blockIdx.x, b = bh >> 4, h = bh & 15;
  const int qbase = blockIdx.y * 64;
  const int nb = nval[b];

  if (tid < 64) {
    int l = qbase + tid;
    km_s[tid] = (l < nb) ? posk[(b << 10) + l] : -1;
  }
  __syncthreads();

  // Q fragments in registers (A-layout: m = c, k = ks*32 + quad*8 + j)
  const unsigned short* qg = qp + (((size_t)bh << 10) + qbase) * 128;
  bf16x8 aq[4];
  #pragma unroll
  for (int ks = 0; ks < 4; ks++)
    aq[ks] = ldfrag(&qg[(size_t)(w * 16 + c) * 128 + ks * 32 + quad * 8]);

  int lv = nb - 1 - qbase; lv = lv > 63 ? 63 : lv;
  const int tile_kmax = (lv >= 0) ? km_s[lv] : -1;
  const int nkt = (tile_kmax >= 0) ? ((tile_kmax >> 6) + 1) : 0;

  // per-wave causal limit (rows ascending -> last row of wave has the max)
  int wl = w * 16 + 15; if (wl > lv) wl = lv;
  const int wkmax = (wl >= w * 16) ? km_s[wl] : -1;

  int km[4];
  #pragma unroll
  for (int r = 0; r < 4; r++) km[r] = km_s[w * 16 + quad * 4 + r];

  // staging source pointers (swizzle keys constant across the i-unroll)
  const int srow = tid >> 4;                       // K: s-local row 0..15 (+16i)
  const int kswz = (tid & 15) ^ (srow & 7);
  const unsigned short* kgp = kp + ((size_t)bh << 11) * 128 + (size_t)srow * 128 + kswz * 8;
  const int dvrow = tid >> 3;                      // V: d-local row 0..31 (+32i)
  const int vswz = (tid & 7) ^ (dvrow & 7);
  const unsigned short* vgp = vtp + ((size_t)bh * 128 + dvrow) * SS + vswz * 8;

  auto STG = [&](int buf, int kb) {
    #pragma unroll
    for (int i = 0; i < 4; i++)
      gl_lds16(kgp + ((size_t)kb + i * 16) * 128, &k_s[buf][(i * 256 + tid) * 8]);
    #pragma unroll
    for (int i = 0; i < 4; i++)
      gl_lds16(vgp + (size_t)kb + (size_t)i * 32 * SS, &vt_s[buf][(i * 256 + tid) * 8]);
  };

  float m_i[4], l_i[4];
  #pragma unroll
  for (int r = 0; r < 4; r++) { m_i[r] = -1e30f; l_i[r] = 0.f; }
  f32x4 o[8];
  #pragma unroll
  for (int dj = 0; dj < 8; dj++) o[dj] = (f32x4){0.f, 0.f, 0.f, 0.f};

  if (nkt > 0) STG(0, 0);

  for (int kt = 0; kt < nkt; kt++) {
    const int cur = kt & 1;
    const int kb = kt * 64;
    if (kt + 1 < nkt) {
      STG(cur ^ 1, kb + 64);                          // prefetch next tile
      asm volatile("s_waitcnt vmcnt(8)" ::: "memory"); // tile kt landed; kt+1 in flight
    } else {
      asm volatile("s_waitcnt vmcnt(0)" ::: "memory");
    }
    __builtin_amdgcn_s_barrier();   // tile kt resident block-wide

    if (kb <= wkmax) {   // wave-uniform causal early-out
      // S = Q K^T
      f32x4 sa[4];
      #pragma unroll
      for (int j = 0; j < 4; j++) {
        sa[j] = (f32x4){0.f, 0.f, 0.f, 0.f};
        #pragma unroll
        for (int ks = 0; ks < 4; ks++) {
          bf16x8 bk = ldfrag(&k_s[cur][((j * 16 + c) << 7) + (((ks * 4 + quad) ^ (c & 7)) << 3)]);
          sa[j] = __builtin_amdgcn_mfma_f32_16x16x32_bf16(aq[ks], bk, sa[j], 0, 0, 0);
        }
      }

      // online softmax (rows live in quads; reduce over 16 lanes via DPP)
      const float scale = 0.08838834764831843f;  // 1/sqrt(128)
      float mt[4] = {-1e30f, -1e30f, -1e30f, -1e30f};
      #pragma unroll
      for (int j = 0; j < 4; j++) {
        int key = kb + j * 16 + c;
        #pragma unroll
        for (int r = 0; r < 4; r++) {
          float v = (key <= km[r]) ? sa[j][r] * scale : -1e30f;
          sa[j][r] = v;
          mt[r] = fmaxf(mt[r], v);
        }
      }
      float al[4], rs[4];
      #pragma unroll
      for (int r = 0; r < 4; r++) {
        mt[r] = rmax16(mt[r]);
        float mn = fmaxf(m_i[r], mt[r]);
        al[r] = __expf(m_i[r] - mn);
        m_i[r] = mn;
        rs[r] = 0.f;
      }
      #pragma unroll
      for (int j = 0; j < 4; j++)
        #pragma unroll
        for (int r = 0; r < 4; r++) {
          float pv = __expf(sa[j][r] - m_i[r]);
          sa[j][r] = pv;
          rs[r] += pv;
        }
      #pragma unroll
      for (int r = 0; r < 4; r++) {
        rs[r] = radd16(rs[r]);
        l_i[r] = l_i[r] * al[r] + rs[r];
      }
      #pragma unroll
      for (int dj = 0; dj < 8; dj++)
        #pragma unroll
        for (int r = 0; r < 4; r++) o[dj][r] *= al[r];

      // P: C-layout -> LDS -> A-layout (per-wave region)
      #pragma unroll
      for (int j = 0; j < 4; j++)
        #pragma unroll
        for (int r = 0; r < 4; r++)
          p_s[w * 1152 + (quad * 4 + r) * 72 + j * 16 + c] = f2bf(sa[j][r]);

      #pragma unroll
      for (int ks2 = 0; ks2 < 2; ks2++) {
        bf16x8 ap = ldfrag(&p_s[w * 1152 + c * 72 + ks2 * 32 + quad * 8]);
        #pragma unroll
        for (int dj = 0; dj < 8; dj++) {
          bf16x8 bv = ldfrag(&vt_s[cur][((dj * 16 + c) << 6) + (((ks2 * 4 + quad) ^ (c & 7)) << 3)]);
          o[dj] = __builtin_amdgcn_mfma_f32_16x16x32_bf16(ap, bv, o[dj], 0, 0, 0);
        }
      }
    }
    __builtin_amdgcn_s_barrier();   // all reads of buf[cur] done before overwrite
  }

  #pragma unroll
  for (int r = 0; r < 4; r++) {
    int l = qbase + w * 16 + quad * 4 + r;
    bool ok = (l < nb);
    float inv = ok ? (1.0f / l_i[r]) : 0.0f;
    #pragma unroll
    for (int dj = 0; dj < 8; dj++)
      ctx[(((size_t)b << 10) + l) * (size_t)DD + h * 128 + dj * 16 + c] =
          f2bf(ok ? o[dj][r] * inv : 0.0f);
  }
}

// ---------------------------------------------------------------------------
extern "C" void kernel_launch(void* const* d_in, const int* in_sizes, int n_in,
                              void* d_out, int out_size, void* d_ws, size_t ws_size,
                              hipStream_t stream) {
  const float* q_src = (const float*)d_in[0];
  const float* k_src = (const float*)d_in[1];
  const float* v_src = (const float*)d_in[2];
  const float* Wq = (const float*)d_in[3];
  const float* Wk = (const float*)d_in[4];
  const float* Wv = (const float*)d_in[5];
  const float* Wo = (const float*)d_in[6];
  const int* skip = (const int*)d_in[9];

  char* p = (char*)d_ws;
  auto alloc = [&](size_t bytes) -> char* {
    char* r = p;
    p += (bytes + 255) & ~(size_t)255;
    return r;
  };
  unsigned short* a_q  = (unsigned short*)alloc((size_t)BB * MAXL * DD * 2);
  unsigned short* a_k  = (unsigned short*)alloc((size_t)BB * SS * DD * 2);
  unsigned short* a_v  = (unsigned short*)alloc((size_t)BB * SS * DD * 2);
  unsigned short* wt_q = (unsigned short*)alloc((size_t)DD * DD * 2);
  unsigned short* wt_k = (unsigned short*)alloc((size_t)DD * DD * 2);
  unsigned short* wt_v = (unsigned short*)alloc((size_t)DD * DD * 2);
  unsigned short* wt_o = (unsigned short*)alloc((size_t)DD * DD * 2);
  unsigned short* q_pro = (unsigned short*)alloc((size_t)BB * HH * MAXL * DHD * 2);
  unsigned short* k_pro = (unsigned short*)alloc((size_t)BB * HH * SS * DHD * 2);
  unsigned short* v_t   = (unsigned short*)alloc((size_t)BB * HH * SS * DHD * 2);
  int* posk = (int*)alloc((size_t)BB * MAXL * 4);
  int* nval = (int*)alloc(64);
  unsigned short* ctx = a_q;  // a_q dead after Q projection

  build_pos<<<BB, 64, 0, stream>>>(skip, posk, nval);
  cvt3<<<(BB * MAXL * DD + 2 * BB * SS * DD) / (4 * 256), 256, 0, stream>>>(
      q_src, k_src, v_src, a_q, a_k, a_v);
  transpose_w4<<<dim3(32, 32, 4), 256, 0, stream>>>(Wq, Wk, Wv, Wo, wt_q, wt_k, wt_v, wt_o);

  gemm8<128><<<dim3(8, 32), 512, 0, stream>>>(a_q, wt_q, q_pro, BB * MAXL, DD, DD, 0, 10);
  gemm8<256><<<dim3(8, 32), 512, 0, stream>>>(a_k, wt_k, k_pro, BB * SS, DD, DD, 0, 11);
  gemm8<256><<<dim3(8, 32), 512, 0, stream>>>(a_v, wt_v, v_t, BB * SS, DD, DD, 2, 11);

  rope2<<<(BB * HH * (MAXL + SS) * 64) / 256, 256, 0, stream>>>(q_pro, k_pro, posk);

  attn_kernel<<<dim3(BB * HH, MAXL / 64), 256, 0, stream>>>(q_pro, k_pro, v_t, posk, nval, ctx);

  gemm8<128><<<dim3(8, 32), 512, 0, stream>>>(ctx, wt_o, d_out, BB * MAXL, DD, DD, 1, 0);
}